// Round 1
// baseline (458.339 us; speedup 1.0000x reference)
//
#include <hip/hip_runtime.h>
#include <stdint.h>

typedef unsigned short u16;
typedef __attribute__((ext_vector_type(4))) float f32x4;
typedef __attribute__((ext_vector_type(8))) __bf16 bf16x8;
typedef __attribute__((ext_vector_type(8))) u16 u16x8;
typedef __attribute__((ext_vector_type(4))) u16 u16x4;

static constexpr int kB = 4, kS = 2048, kD = 1024, kH = 16, kHD = 64;
static constexpr int M1 = kB * kS;   // 8192
static constexpr int N1 = 3 * kD;    // 3072
static constexpr int K1 = kD;        // 1024

__device__ __forceinline__ u16 f2bf(float f) {
  union { float f; uint32_t u; } c; c.f = f;
  uint32_t u = c.u + 0x7FFFu + ((c.u >> 16) & 1u);   // RNE
  return (u16)(u >> 16);
}

__device__ __forceinline__ void gload_lds16(const u16* g, u16* l) {
  __builtin_amdgcn_global_load_lds(
      (const __attribute__((address_space(1))) unsigned int*)g,
      (__attribute__((address_space(3))) unsigned int*)l, 16, 0, 0);
}

// ---------------- cast kernels ----------------
__global__ __launch_bounds__(256) void k_cast_x(const float* __restrict__ x,
                                                u16* __restrict__ o) {
  int i = (blockIdx.x * 256 + threadIdx.x) * 4;
  f32x4 v = *(const f32x4*)(x + i);
  u16x4 r;
  r[0] = f2bf(v[0]); r[1] = f2bf(v[1]); r[2] = f2bf(v[2]); r[3] = f2bf(v[3]);
  *(u16x4*)(o + i) = r;
}

// w: [K][N] f32  ->  wt: [N][K] bf16   (B^T layout for GEMM)
__global__ __launch_bounds__(256) void k_transpose_cast(const float* __restrict__ w,
                                                        u16* __restrict__ wt,
                                                        int K, int N) {
  __shared__ float t[32][33];
  const int n0 = blockIdx.x * 32, k0 = blockIdx.y * 32;
  const int tx = threadIdx.x & 31, ty = threadIdx.x >> 5;
  for (int r = ty; r < 32; r += 8)
    t[r][tx] = w[(size_t)(k0 + r) * N + n0 + tx];
  __syncthreads();
  for (int r = ty; r < 32; r += 8)
    wt[(size_t)(n0 + r) * K + k0 + tx] = f2bf(t[tx][r]);
}

// ---------------- GEMM (A row-major MxK, BT row-major NxK) ----------------
// MODE 0: epilogue scatters bf16 into QKV [3][B][H][S][HD]
// MODE 1: epilogue writes f32 row-major [M][N]
template <int MODE>
__global__ __launch_bounds__(256) void k_gemm_bt(const u16* __restrict__ A,
                                                 const u16* __restrict__ BT,
                                                 u16* __restrict__ obf,
                                                 float* __restrict__ of,
                                                 int M, int N, int K) {
  __shared__ __align__(16) u16 As[128 * 32];
  __shared__ __align__(16) u16 Bs[128 * 32];
  const int tid = threadIdx.x;
  const int wave = tid >> 6, lane = tid & 63;
  const int l15 = lane & 15, l16 = lane >> 4;
  const int row0 = blockIdx.y * 128, col0 = blockIdx.x * 128;
  const int wm = (wave >> 1) * 64, wn = (wave & 1) * 64;

  f32x4 acc[4][4];
#pragma unroll
  for (int i = 0; i < 4; ++i)
#pragma unroll
    for (int j = 0; j < 4; ++j) acc[i][j] = f32x4{0.f, 0.f, 0.f, 0.f};

  // staging map: element e = it*2048 + wave*512 + lane*8 ; r=e/32, c=e%32
  const int e0 = wave * 512 + lane * 8;
  const int r0 = e0 >> 5, c0 = e0 & 31;
  const int e1 = e0 + 2048;
  const int r1 = e1 >> 5, c1 = e1 & 31;
  const u16* Ab = A + (size_t)row0 * K;
  const u16* Bb = BT + (size_t)col0 * K;

  for (int kt = 0; kt < K; kt += 32) {
    gload_lds16(Ab + (size_t)r0 * K + kt + c0, &As[wave * 512]);
    gload_lds16(Ab + (size_t)r1 * K + kt + c1, &As[2048 + wave * 512]);
    gload_lds16(Bb + (size_t)r0 * K + kt + c0, &Bs[wave * 512]);
    gload_lds16(Bb + (size_t)r1 * K + kt + c1, &Bs[2048 + wave * 512]);
    __syncthreads();
    bf16x8 af[4], bfv[4];
#pragma unroll
    for (int f = 0; f < 4; ++f) {
      af[f]  = *(const bf16x8*)&As[(wm + f * 16 + l15) * 32 + l16 * 8];
      bfv[f] = *(const bf16x8*)&Bs[(wn + f * 16 + l15) * 32 + l16 * 8];
    }
#pragma unroll
    for (int fm = 0; fm < 4; ++fm)
#pragma unroll
      for (int fn = 0; fn < 4; ++fn)
        acc[fm][fn] = __builtin_amdgcn_mfma_f32_16x16x32_bf16(af[fm], bfv[fn],
                                                              acc[fm][fn], 0, 0, 0);
    __syncthreads();
  }

#pragma unroll
  for (int fm = 0; fm < 4; ++fm)
#pragma unroll
    for (int fn = 0; fn < 4; ++fn) {
      const int n = col0 + wn + fn * 16 + l15;
#pragma unroll
      for (int j = 0; j < 4; ++j) {
        const int m = row0 + wm + fm * 16 + l16 * 4 + j;
        float v = acc[fm][fn][j];
        if constexpr (MODE == 0) {
          const int which = n >> 10, d = n & 1023;
          const int h = d >> 6, hd = d & 63;
          const int b = m >> 11, s = m & 2047;
          obf[((((size_t)which * 4 + b) * 16 + h) * 2048 + s) * 64 + hd] = f2bf(v);
        } else {
          of[(size_t)m * N + n] = v;
        }
      }
    }
}

// ---------------- flash attention ----------------
// grid: x = S/64 (q block), y = B*H. 4 waves; wave w owns q rows [s0+16w, s0+16w+16)
__global__ __launch_bounds__(256) void k_attn(const u16* __restrict__ Qg,
                                              const u16* __restrict__ Kg,
                                              const u16* __restrict__ Vg,
                                              u16* __restrict__ ctx) {
  const int qb = blockIdx.x, bh = blockIdx.y;
  const int bb = bh >> 4, hh = bh & 15;
  const int tid = threadIdx.x;
  const int wave = tid >> 6, lane = tid & 63;
  const int l15 = lane & 15, l16 = lane >> 4;
  const int s0 = qb * 64;
  const int qrow = s0 + wave * 16;

  __shared__ __align__(16) u16 Vt[64 * 40];       // V^T, padded stride 40
  __shared__ __align__(16) u16 Pl[4 * 16 * 40];   // per-wave P scratch

  const u16* Qb = Qg + (size_t)bh * kS * kHD;
  const u16* Kb = Kg + (size_t)bh * kS * kHD;
  const u16* Vb = Vg + (size_t)bh * kS * kHD;

  bf16x8 aq[2];
#pragma unroll
  for (int c = 0; c < 2; ++c)
    aq[c] = *(const bf16x8*)(Qb + (size_t)(qrow + l15) * 64 + c * 32 + l16 * 8);

  f32x4 acco[4];
#pragma unroll
  for (int i = 0; i < 4; ++i) acco[i] = f32x4{0.f, 0.f, 0.f, 0.f};
  float mrow[4] = {-1e30f, -1e30f, -1e30f, -1e30f};
  float lrow[4] = {0.f, 0.f, 0.f, 0.f};

  const int nkv = s0 + 64;
  for (int kv0 = 0; kv0 < nkv; kv0 += 32) {
    __syncthreads();  // previous tile's PV reads of Vt done
    {
      const int key = tid & 31, d0 = (tid >> 5) * 8;
      u16x8 v = *(const u16x8*)(Vb + (size_t)(kv0 + key) * 64 + d0);
#pragma unroll
      for (int i = 0; i < 8; ++i) Vt[(d0 + i) * 40 + key] = v[i];
    }
    __syncthreads();

    // S = Q K^T  (two 16-key column groups)
    f32x4 accs[2];
#pragma unroll
    for (int kc = 0; kc < 2; ++kc) {
      accs[kc] = f32x4{0.f, 0.f, 0.f, 0.f};
      const int key = kv0 + kc * 16 + l15;
#pragma unroll
      for (int dr = 0; dr < 2; ++dr) {
        bf16x8 bk = *(const bf16x8*)(Kb + (size_t)key * 64 + dr * 32 + l16 * 8);
        accs[kc] = __builtin_amdgcn_mfma_f32_16x16x32_bf16(aq[dr], bk, accs[kc], 0, 0, 0);
      }
    }

    // mask + online softmax (rows live at (l16*4+j), cols at l15)
    float sv[2][4], tmax[4];
#pragma unroll
    for (int j = 0; j < 4; ++j) tmax[j] = -1e30f;
#pragma unroll
    for (int kc = 0; kc < 2; ++kc) {
      const int key = kv0 + kc * 16 + l15;
#pragma unroll
      for (int j = 0; j < 4; ++j) {
        const int q = qrow + l16 * 4 + j;
        float s = accs[kc][j] * 0.125f;
        s = (key <= q) ? s : -1e30f;
        sv[kc][j] = s;
        tmax[j] = fmaxf(tmax[j], s);
      }
    }
#pragma unroll
    for (int off = 8; off >= 1; off >>= 1)
#pragma unroll
      for (int j = 0; j < 4; ++j)
        tmax[j] = fmaxf(tmax[j], __shfl_xor(tmax[j], off, 64));

    float sc[4], p0[4], p1[4], psum[4];
#pragma unroll
    for (int j = 0; j < 4; ++j) {
      float mn = fmaxf(mrow[j], tmax[j]);
      sc[j] = __expf(mrow[j] - mn);
      mrow[j] = mn;
      p0[j] = __expf(sv[0][j] - mn);
      p1[j] = __expf(sv[1][j] - mn);
      psum[j] = p0[j] + p1[j];
    }
#pragma unroll
    for (int off = 8; off >= 1; off >>= 1)
#pragma unroll
      for (int j = 0; j < 4; ++j)
        psum[j] += __shfl_xor(psum[j], off, 64);
#pragma unroll
    for (int j = 0; j < 4; ++j) {
      lrow[j] = lrow[j] * sc[j] + psum[j];
#pragma unroll
      for (int df = 0; df < 4; ++df) acco[df][j] *= sc[j];
      const int prow = l16 * 4 + j;
      Pl[wave * 640 + prow * 40 + l15] = f2bf(p0[j]);
      Pl[wave * 640 + prow * 40 + 16 + l15] = f2bf(p1[j]);
    }

    // O += P V   (P: 16x32 A-frag from LDS; V^T: B-frags from LDS)
    bf16x8 pf = *(const bf16x8*)&Pl[wave * 640 + l15 * 40 + l16 * 8];
#pragma unroll
    for (int df = 0; df < 4; ++df) {
      bf16x8 vf = *(const bf16x8*)&Vt[(df * 16 + l15) * 40 + l16 * 8];
      acco[df] = __builtin_amdgcn_mfma_f32_16x16x32_bf16(pf, vf, acco[df], 0, 0, 0);
    }
  }

#pragma unroll
  for (int df = 0; df < 4; ++df)
#pragma unroll
    for (int j = 0; j < 4; ++j) {
      const int srow = qrow + l16 * 4 + j;
      const int col = hh * 64 + df * 16 + l15;
      float v = acco[df][j] / lrow[j];
      ctx[((size_t)bb * kS + srow) * kD + col] = f2bf(v);
    }
}

// ---------------- launcher ----------------
extern "C" void kernel_launch(void* const* d_in, const int* in_sizes, int n_in,
                              void* d_out, int out_size, void* d_ws, size_t ws_size,
                              hipStream_t stream) {
  const float* x     = (const float*)d_in[0];
  const float* w_qkv = (const float*)d_in[1];
  const float* w_out = (const float*)d_in[2];
  float* out = (float*)d_out;

  u16* ws    = (u16*)d_ws;
  u16* x_bf  = ws;                                  // 8192*1024
  u16* wqkvT = x_bf + (size_t)M1 * K1;              // 3072*1024
  u16* woutT = wqkvT + (size_t)N1 * K1;             // 1024*1024
  u16* qkv   = woutT + (size_t)kD * kD;             // 3 * 64*2048*64
  u16* ctx   = qkv + (size_t)3 * kB * kH * kS * kHD;  // 8192*1024

  k_cast_x<<<M1 * K1 / 1024, 256, 0, stream>>>(x, x_bf);
  k_transpose_cast<<<dim3(N1 / 32, K1 / 32), 256, 0, stream>>>(w_qkv, wqkvT, K1, N1);
  k_transpose_cast<<<dim3(kD / 32, kD / 32), 256, 0, stream>>>(w_out, woutT, kD, kD);

  k_gemm_bt<0><<<dim3(N1 / 128, M1 / 128), 256, 0, stream>>>(x_bf, wqkvT, qkv, nullptr,
                                                             M1, N1, K1);

  const u16* Qg = qkv;
  const u16* Kg = qkv + (size_t)kB * kH * kS * kHD;
  const u16* Vg = qkv + (size_t)2 * kB * kH * kS * kHD;
  k_attn<<<dim3(kS / 64, kB * kH), 256, 0, stream>>>(Qg, Kg, Vg, ctx);

  k_gemm_bt<1><<<dim3(kD / 128, M1 / 128), 256, 0, stream>>>(ctx, woutT, nullptr, out,
                                                             M1, kD, K1);
}

// Round 2
// 450.880 us; speedup vs baseline: 1.0165x; 1.0165x over previous
//
#include <hip/hip_runtime.h>
#include <stdint.h>

typedef unsigned short u16;
typedef __attribute__((ext_vector_type(4))) float f32x4;
typedef __attribute__((ext_vector_type(8))) __bf16 bf16x8;
typedef __attribute__((ext_vector_type(8))) u16 u16x8;
typedef __attribute__((ext_vector_type(4))) u16 u16x4;

static constexpr int kB = 4, kS = 2048, kD = 1024, kH = 16, kHD = 64;
static constexpr int M1 = kB * kS;   // 8192
static constexpr int N1 = 3 * kD;    // 3072
static constexpr int K1 = kD;        // 1024

__device__ __forceinline__ u16 f2bf(float f) {
  union { float f; uint32_t u; } c; c.f = f;
  uint32_t u = c.u + 0x7FFFu + ((c.u >> 16) & 1u);   // RNE
  return (u16)(u >> 16);
}

__device__ __forceinline__ void gload_lds16(const u16* g, u16* l) {
  __builtin_amdgcn_global_load_lds(
      (const __attribute__((address_space(1))) unsigned int*)g,
      (__attribute__((address_space(3))) unsigned int*)l, 16, 0, 0);
}

// ---------------- cast kernels ----------------
__global__ __launch_bounds__(256) void k_cast_x(const float* __restrict__ x,
                                                u16* __restrict__ o) {
  int i = (blockIdx.x * 256 + threadIdx.x) * 4;
  f32x4 v = *(const f32x4*)(x + i);
  u16x4 r;
  r[0] = f2bf(v[0]); r[1] = f2bf(v[1]); r[2] = f2bf(v[2]); r[3] = f2bf(v[3]);
  *(u16x4*)(o + i) = r;
}

// w: [K][N] f32  ->  wt: [N][K] bf16   (B^T layout for GEMM)
__global__ __launch_bounds__(256) void k_transpose_cast(const float* __restrict__ w,
                                                        u16* __restrict__ wt,
                                                        int K, int N) {
  __shared__ float t[32][33];
  const int n0 = blockIdx.x * 32, k0 = blockIdx.y * 32;
  const int tx = threadIdx.x & 31, ty = threadIdx.x >> 5;
  for (int r = ty; r < 32; r += 8)
    t[r][tx] = w[(size_t)(k0 + r) * N + n0 + tx];
  __syncthreads();
  for (int r = ty; r < 32; r += 8)
    wt[(size_t)(n0 + r) * K + k0 + tx] = f2bf(t[tx][r]);
}

// ---------------- GEMM (A row-major MxK, BT row-major NxK) ----------------
template <int MODE>
__global__ __launch_bounds__(256) void k_gemm_bt(const u16* __restrict__ A,
                                                 const u16* __restrict__ BT,
                                                 u16* __restrict__ obf,
                                                 float* __restrict__ of,
                                                 int M, int N, int K) {
  __shared__ __align__(16) u16 As[128 * 32];
  __shared__ __align__(16) u16 Bs[128 * 32];
  const int tid = threadIdx.x;
  const int wave = tid >> 6, lane = tid & 63;
  const int l15 = lane & 15, l16 = lane >> 4;
  const int row0 = blockIdx.y * 128, col0 = blockIdx.x * 128;
  const int wm = (wave >> 1) * 64, wn = (wave & 1) * 64;

  f32x4 acc[4][4];
#pragma unroll
  for (int i = 0; i < 4; ++i)
#pragma unroll
    for (int j = 0; j < 4; ++j) acc[i][j] = f32x4{0.f, 0.f, 0.f, 0.f};

  const int e0 = wave * 512 + lane * 8;
  const int r0 = e0 >> 5, c0 = e0 & 31;
  const int e1 = e0 + 2048;
  const int r1 = e1 >> 5, c1 = e1 & 31;
  const u16* Ab = A + (size_t)row0 * K;
  const u16* Bb = BT + (size_t)col0 * K;

  for (int kt = 0; kt < K; kt += 32) {
    gload_lds16(Ab + (size_t)r0 * K + kt + c0, &As[wave * 512]);
    gload_lds16(Ab + (size_t)r1 * K + kt + c1, &As[2048 + wave * 512]);
    gload_lds16(Bb + (size_t)r0 * K + kt + c0, &Bs[wave * 512]);
    gload_lds16(Bb + (size_t)r1 * K + kt + c1, &Bs[2048 + wave * 512]);
    __syncthreads();
    bf16x8 af[4], bfv[4];
#pragma unroll
    for (int f = 0; f < 4; ++f) {
      af[f]  = *(const bf16x8*)&As[(wm + f * 16 + l15) * 32 + l16 * 8];
      bfv[f] = *(const bf16x8*)&Bs[(wn + f * 16 + l15) * 32 + l16 * 8];
    }
#pragma unroll
    for (int fm = 0; fm < 4; ++fm)
#pragma unroll
      for (int fn = 0; fn < 4; ++fn)
        acc[fm][fn] = __builtin_amdgcn_mfma_f32_16x16x32_bf16(af[fm], bfv[fn],
                                                              acc[fm][fn], 0, 0, 0);
    __syncthreads();
  }

#pragma unroll
  for (int fm = 0; fm < 4; ++fm)
#pragma unroll
    for (int fn = 0; fn < 4; ++fn) {
      const int n = col0 + wn + fn * 16 + l15;
#pragma unroll
      for (int j = 0; j < 4; ++j) {
        const int m = row0 + wm + fm * 16 + l16 * 4 + j;
        float v = acc[fm][fn][j];
        if constexpr (MODE == 0) {
          const int which = n >> 10, d = n & 1023;
          const int h = d >> 6, hd = d & 63;
          const int b = m >> 11, s = m & 2047;
          obf[((((size_t)which * 4 + b) * 16 + h) * 2048 + s) * 64 + hd] = f2bf(v);
        } else {
          of[(size_t)m * N + n] = v;
        }
      }
    }
}

// ---------------- flash attention v2 ----------------
// grid: x = S/128 (q block, reversed for largest-first), y = B*H
// 4 waves; wave w owns 32 q rows [s0+32w, s0+32w+32). KV tile = 64.
// K: LDS double-buffered via global_load_lds, XOR-swizzled via pre-swizzled src.
// V^T, P: LDS, XOR-swizzled, with key->pos permutation pos=(key&15)*4+(key>>4)
// applied to BOTH (PV contraction is permutation-invariant).
__global__ __launch_bounds__(256) void k_attn(const u16* __restrict__ Qg,
                                              const u16* __restrict__ Kg,
                                              const u16* __restrict__ Vg,
                                              u16* __restrict__ ctx) {
  __shared__ __align__(16) u16 Ks[2][64 * 64];
  __shared__ __align__(16) u16 Vt[64 * 64];
  __shared__ __align__(16) u16 Pl[4][32 * 64];

  const int qb = (gridDim.x - 1) - blockIdx.x;
  const int bh = blockIdx.y;
  const int bb = bh >> 4, hh = bh & 15;
  const int tid = threadIdx.x;
  const int wave = tid >> 6, lane = tid & 63;
  const int l15 = lane & 15, l16 = lane >> 4;
  const int s0 = qb * 128;
  const int qstart = s0 + wave * 32;
  u16* Pw = &Pl[wave][0];

  const u16* Qb = Qg + (size_t)bh * kS * kHD;
  const u16* Kb = Kg + (size_t)bh * kS * kHD;
  const u16* Vb = Vg + (size_t)bh * kS * kHD;

  const float SCL = 0.125f * 1.44269504f;  // 1/sqrt(64) * log2(e)

  // Q fragments: aq[rf][s]  (rows qstart+rf*16+l15, k = s*32+l16*8)
  bf16x8 aq[2][2];
#pragma unroll
  for (int rf = 0; rf < 2; ++rf)
#pragma unroll
    for (int s = 0; s < 2; ++s)
      aq[rf][s] = *(const bf16x8*)(Qb + (size_t)(qstart + rf * 16 + l15) * 64 +
                                   s * 32 + l16 * 8);

  f32x4 acco[2][4];
#pragma unroll
  for (int rf = 0; rf < 2; ++rf)
#pragma unroll
    for (int df = 0; df < 4; ++df) acco[rf][df] = f32x4{0.f, 0.f, 0.f, 0.f};
  float mrow[2][4], lrow[2][4];
#pragma unroll
  for (int rf = 0; rf < 2; ++rf)
#pragma unroll
    for (int j = 0; j < 4; ++j) { mrow[rf][j] = -1e30f; lrow[rf][j] = 0.f; }

  const int ntiles = 2 * qb + 2;

  // staging indices (per thread): granule g = r*256 + tid
  const int gk0 = tid >> 3;           // key for r=0
  const int gs0 = tid & 7;            // slot for r=0
  u16x8 vreg[2];

  // ---- prologue: stage K(0), load V(0) regs ----
#pragma unroll
  for (int r = 0; r < 2; ++r) {
    const int key = r * 32 + gk0;
    const int sslot = gs0 ^ (key & 7);
    gload_lds16(Kb + (size_t)key * 64 + sslot * 8, &Ks[0][r * 2048 + wave * 512]);
    vreg[r] = *(const u16x8*)(Vb + (size_t)key * 64 + gs0 * 8);
  }

  for (int t = 0; t < ntiles; ++t) {
    const int kv0 = t * 64;
    __syncthreads();  // prev compute done reading Vt/P; K(t),V(t) loads drained

    // store V(t)^T into LDS (permuted + swizzled)
#pragma unroll
    for (int r = 0; r < 2; ++r) {
      const int key = r * 32 + gk0;
      const int pos = ((key & 15) << 2) | (key >> 4);
      const int ds0 = gs0 * 8;
#pragma unroll
      for (int i = 0; i < 8; ++i) {
        const int d = ds0 + i;
        Vt[d * 64 + (pos ^ ((d & 7) << 3))] = vreg[r][i];
      }
    }
    __syncthreads();  // Vt ready (Ks[t&1] ready since previous barrier)

    // issue next tile's loads: they drain at NEXT iteration's first barrier,
    // i.e. the latency hides under this tile's compute.
    if (t + 1 < ntiles) {
      const int nkv = kv0 + 64;
#pragma unroll
      for (int r = 0; r < 2; ++r) {
        const int key = r * 32 + gk0;
        const int sslot = gs0 ^ (key & 7);
        gload_lds16(Kb + (size_t)(nkv + key) * 64 + sslot * 8,
                    &Ks[(t + 1) & 1][r * 2048 + wave * 512]);
        vreg[r] = *(const u16x8*)(Vb + (size_t)(nkv + key) * 64 + gs0 * 8);
      }
    }

    if (kv0 <= qstart + 31) {  // tile not fully masked for this wave
      const u16* Kbuf = &Ks[t & 1][0];
      // ---- QK^T ----
      f32x4 accs[2][4];
#pragma unroll
      for (int rf = 0; rf < 2; ++rf)
#pragma unroll
        for (int kc = 0; kc < 4; ++kc) accs[rf][kc] = f32x4{0.f, 0.f, 0.f, 0.f};
#pragma unroll
      for (int s = 0; s < 2; ++s) {
#pragma unroll
        for (int kc = 0; kc < 4; ++kc) {
          const int key = kc * 16 + l15;
          const int gsl = (s * 4 + l16) ^ (key & 7);
          bf16x8 bk = *(const bf16x8*)&Kbuf[key * 64 + gsl * 8];
          accs[0][kc] = __builtin_amdgcn_mfma_f32_16x16x32_bf16(aq[0][s], bk, accs[0][kc], 0, 0, 0);
          accs[1][kc] = __builtin_amdgcn_mfma_f32_16x16x32_bf16(aq[1][s], bk, accs[1][kc], 0, 0, 0);
        }
      }

      // ---- online softmax (log2 domain) ----
      const bool needmask = (kv0 + 63 > qstart);
      float scj[2][4];
#pragma unroll
      for (int rf = 0; rf < 2; ++rf) {
#pragma unroll
        for (int j = 0; j < 4; ++j) {
          const int q = qstart + rf * 16 + l16 * 4 + j;
          float s0v = accs[rf][0][j] * SCL;
          float s1v = accs[rf][1][j] * SCL;
          float s2v = accs[rf][2][j] * SCL;
          float s3v = accs[rf][3][j] * SCL;
          if (needmask) {
            const int keyb = kv0 + l15;
            s0v = (keyb      <= q) ? s0v : -3e38f;
            s1v = (keyb + 16 <= q) ? s1v : -3e38f;
            s2v = (keyb + 32 <= q) ? s2v : -3e38f;
            s3v = (keyb + 48 <= q) ? s3v : -3e38f;
          }
          float tm = fmaxf(fmaxf(s0v, s1v), fmaxf(s2v, s3v));
#pragma unroll
          for (int off = 1; off <= 8; off <<= 1)
            tm = fmaxf(tm, __shfl_xor(tm, off, 64));
          const float mn = fmaxf(mrow[rf][j], tm);
          const float sc = exp2f(mrow[rf][j] - mn);
          mrow[rf][j] = mn;
          const float p0 = exp2f(s0v - mn), p1 = exp2f(s1v - mn);
          const float p2 = exp2f(s2v - mn), p3 = exp2f(s3v - mn);
          float ps = (p0 + p1) + (p2 + p3);
#pragma unroll
          for (int off = 1; off <= 8; off <<= 1)
            ps += __shfl_xor(ps, off, 64);
          lrow[rf][j] = lrow[rf][j] * sc + ps;
          scj[rf][j] = sc;
          const int row = rf * 16 + l16 * 4 + j;
          u16x4 pk;
          pk[0] = f2bf(p0); pk[1] = f2bf(p1); pk[2] = f2bf(p2); pk[3] = f2bf(p3);
          *(u16x4*)&Pw[row * 64 + ((l15 * 4) ^ ((row & 7) << 3))] = pk;
        }
      }
#pragma unroll
      for (int rf = 0; rf < 2; ++rf)
#pragma unroll
        for (int df = 0; df < 4; ++df)
#pragma unroll
          for (int j = 0; j < 4; ++j) acco[rf][df][j] *= scj[rf][j];

      // ---- PV ----
#pragma unroll
      for (int s = 0; s < 2; ++s) {
        const int gsl = (s * 4 + l16) ^ (l15 & 7);
        bf16x8 pf[2];
#pragma unroll
        for (int rf = 0; rf < 2; ++rf)
          pf[rf] = *(const bf16x8*)&Pw[(rf * 16 + l15) * 64 + gsl * 8];
#pragma unroll
        for (int df = 0; df < 4; ++df) {
          bf16x8 vf = *(const bf16x8*)&Vt[(df * 16 + l15) * 64 + gsl * 8];
          acco[0][df] = __builtin_amdgcn_mfma_f32_16x16x32_bf16(pf[0], vf, acco[0][df], 0, 0, 0);
          acco[1][df] = __builtin_amdgcn_mfma_f32_16x16x32_bf16(pf[1], vf, acco[1][df], 0, 0, 0);
        }
      }
    }
  }

  // ---- epilogue ----
#pragma unroll
  for (int rf = 0; rf < 2; ++rf)
#pragma unroll
    for (int j = 0; j < 4; ++j) {
      const float rl = 1.0f / lrow[rf][j];
      const int srow = qstart + rf * 16 + l16 * 4 + j;
#pragma unroll
      for (int df = 0; df < 4; ++df) {
        const int col = hh * 64 + df * 16 + l15;
        ctx[((size_t)bb * kS + srow) * kD + col] = f2bf(acco[rf][df][j] * rl);
      }
    }
}

// ---------------- launcher ----------------
extern "C" void kernel_launch(void* const* d_in, const int* in_sizes, int n_in,
                              void* d_out, int out_size, void* d_ws, size_t ws_size,
                              hipStream_t stream) {
  const float* x     = (const float*)d_in[0];
  const float* w_qkv = (const float*)d_in[1];
  const float* w_out = (const float*)d_in[2];
  float* out = (float*)d_out;

  u16* ws    = (u16*)d_ws;
  u16* x_bf  = ws;                                  // 8192*1024
  u16* wqkvT = x_bf + (size_t)M1 * K1;              // 3072*1024
  u16* woutT = wqkvT + (size_t)N1 * K1;             // 1024*1024
  u16* qkv   = woutT + (size_t)kD * kD;             // 3 * 64*2048*64
  u16* ctx   = qkv + (size_t)3 * kB * kH * kS * kHD;  // 8192*1024

  k_cast_x<<<M1 * K1 / 1024, 256, 0, stream>>>(x, x_bf);
  k_transpose_cast<<<dim3(N1 / 32, K1 / 32), 256, 0, stream>>>(w_qkv, wqkvT, K1, N1);
  k_transpose_cast<<<dim3(kD / 32, kD / 32), 256, 0, stream>>>(w_out, woutT, kD, kD);

  k_gemm_bt<0><<<dim3(N1 / 128, M1 / 128), 256, 0, stream>>>(x_bf, wqkvT, qkv, nullptr,
                                                             M1, N1, K1);

  const u16* Qg = qkv;
  const u16* Kg = qkv + (size_t)kB * kH * kS * kHD;
  const u16* Vg = qkv + (size_t)2 * kB * kH * kS * kHD;
  k_attn<<<dim3(kS / 128, kB * kH), 256, 0, stream>>>(Qg, Kg, Vg, ctx);

  k_gemm_bt<1><<<dim3(kD / 128, M1 / 128), 256, 0, stream>>>(ctx, woutT, nullptr, out,
                                                             M1, kD, K1);
}

// Round 3
// 222.242 us; speedup vs baseline: 2.0623x; 2.0288x over previous
//
#include <hip/hip_runtime.h>
#include <stdint.h>

typedef unsigned short u16;
typedef __attribute__((ext_vector_type(4))) float f32x4;
typedef __attribute__((ext_vector_type(16))) float f32x16;
typedef __attribute__((ext_vector_type(8))) __bf16 bf16x8;
typedef __attribute__((ext_vector_type(8))) u16 u16x8;
typedef __attribute__((ext_vector_type(4))) u16 u16x4;

static constexpr int kB = 4, kS = 2048, kD = 1024, kH = 16, kHD = 64;
static constexpr int M1 = kB * kS;   // 8192
static constexpr int N1 = 3 * kD;    // 3072
static constexpr int K1 = kD;        // 1024

__device__ __forceinline__ u16 f2bf(float f) {
  union { float f; uint32_t u; } c; c.f = f;
  uint32_t u = c.u + 0x7FFFu + ((c.u >> 16) & 1u);   // RNE
  return (u16)(u >> 16);
}

__device__ __forceinline__ unsigned pkbf(float a, float b) {
  union { __bf16 h[2]; unsigned u; } c;
  c.h[0] = (__bf16)a; c.h[1] = (__bf16)b;
  return c.u;
}

__device__ __forceinline__ f32x16 zero16() {
  f32x16 v;
#pragma unroll
  for (int i = 0; i < 16; ++i) v[i] = 0.f;
  return v;
}

__device__ __forceinline__ void gload_lds16(const u16* g, u16* l) {
  __builtin_amdgcn_global_load_lds(
      (const __attribute__((address_space(1))) unsigned int*)g,
      (__attribute__((address_space(3))) unsigned int*)l, 16, 0, 0);
}

// ---------------- cast kernels ----------------
__global__ __launch_bounds__(256) void k_cast_x(const float* __restrict__ x,
                                                u16* __restrict__ o) {
  int i = (blockIdx.x * 256 + threadIdx.x) * 4;
  f32x4 v = *(const f32x4*)(x + i);
  u16x4 r;
  r[0] = f2bf(v[0]); r[1] = f2bf(v[1]); r[2] = f2bf(v[2]); r[3] = f2bf(v[3]);
  *(u16x4*)(o + i) = r;
}

// w: [K][N] f32  ->  wt: [N][K] bf16   (B^T layout for GEMM)
__global__ __launch_bounds__(256) void k_transpose_cast(const float* __restrict__ w,
                                                        u16* __restrict__ wt,
                                                        int K, int N) {
  __shared__ float t[32][33];
  const int n0 = blockIdx.x * 32, k0 = blockIdx.y * 32;
  const int tx = threadIdx.x & 31, ty = threadIdx.x >> 5;
  for (int r = ty; r < 32; r += 8)
    t[r][tx] = w[(size_t)(k0 + r) * N + n0 + tx];
  __syncthreads();
  for (int r = ty; r < 32; r += 8)
    wt[(size_t)(n0 + r) * K + k0 + tx] = f2bf(t[tx][r]);
}

// ---------------- GEMM (A row-major MxK, BT row-major NxK) ----------------
template <int MODE>
__global__ __launch_bounds__(256) void k_gemm_bt(const u16* __restrict__ A,
                                                 const u16* __restrict__ BT,
                                                 u16* __restrict__ obf,
                                                 float* __restrict__ of,
                                                 int M, int N, int K) {
  typedef __attribute__((ext_vector_type(4))) float f4;
  __shared__ __align__(16) u16 As[128 * 32];
  __shared__ __align__(16) u16 Bs[128 * 32];
  const int tid = threadIdx.x;
  const int wave = tid >> 6, lane = tid & 63;
  const int l15 = lane & 15, l16 = lane >> 4;
  const int row0 = blockIdx.y * 128, col0 = blockIdx.x * 128;
  const int wm = (wave >> 1) * 64, wn = (wave & 1) * 64;

  f4 acc[4][4];
#pragma unroll
  for (int i = 0; i < 4; ++i)
#pragma unroll
    for (int j = 0; j < 4; ++j) acc[i][j] = f4{0.f, 0.f, 0.f, 0.f};

  const int e0 = wave * 512 + lane * 8;
  const int r0 = e0 >> 5, c0 = e0 & 31;
  const int e1 = e0 + 2048;
  const int r1 = e1 >> 5, c1 = e1 & 31;
  const u16* Ab = A + (size_t)row0 * K;
  const u16* Bb = BT + (size_t)col0 * K;

  for (int kt = 0; kt < K; kt += 32) {
    gload_lds16(Ab + (size_t)r0 * K + kt + c0, &As[wave * 512]);
    gload_lds16(Ab + (size_t)r1 * K + kt + c1, &As[2048 + wave * 512]);
    gload_lds16(Bb + (size_t)r0 * K + kt + c0, &Bs[wave * 512]);
    gload_lds16(Bb + (size_t)r1 * K + kt + c1, &Bs[2048 + wave * 512]);
    __syncthreads();
    bf16x8 af[4], bfv[4];
#pragma unroll
    for (int f = 0; f < 4; ++f) {
      af[f]  = *(const bf16x8*)&As[(wm + f * 16 + l15) * 32 + l16 * 8];
      bfv[f] = *(const bf16x8*)&Bs[(wn + f * 16 + l15) * 32 + l16 * 8];
    }
#pragma unroll
    for (int fm = 0; fm < 4; ++fm)
#pragma unroll
      for (int fn = 0; fn < 4; ++fn)
        acc[fm][fn] = __builtin_amdgcn_mfma_f32_16x16x32_bf16(af[fm], bfv[fn],
                                                              acc[fm][fn], 0, 0, 0);
    __syncthreads();
  }

#pragma unroll
  for (int fm = 0; fm < 4; ++fm)
#pragma unroll
    for (int fn = 0; fn < 4; ++fn) {
      const int n = col0 + wn + fn * 16 + l15;
#pragma unroll
      for (int j = 0; j < 4; ++j) {
        const int m = row0 + wm + fm * 16 + l16 * 4 + j;
        float v = acc[fm][fn][j];
        if constexpr (MODE == 0) {
          const int which = n >> 10, d = n & 1023;
          const int h = d >> 6, hd = d & 63;
          const int b = m >> 11, s = m & 2047;
          obf[((((size_t)which * 4 + b) * 16 + h) * 2048 + s) * 64 + hd] = f2bf(v);
        } else {
          of[(size_t)m * N + n] = v;
        }
      }
    }
}

// ---------------- flash attention v3 (swapped 32x32) ----------------
// grid: x = 8 (pair index), y = B*H.  Block does q-superblocks {p, 15-p}
// (128 rows each, 4 waves x 32 rows) -> uniform 34 tiles/block.
// S^T = mfma(K, Q): lane owns q = qstart + (lane&31); keys in regs.
// O^T = mfma(Vt_frag, P_frag): acc cols = q -> m/l/rescale all lane-local.
// K: LDS dbuf via global_load_lds w/ pre-swizzled source (slot ^= key&7).
// V: key-pair u32 LDS dbuf, swizzle kp ^= ((d&7)^(d>>3))<<2 (full 32-bank).
__global__ __launch_bounds__(256, 2) void k_attn(const u16* __restrict__ Qg,
                                                 const u16* __restrict__ Kg,
                                                 const u16* __restrict__ Vg,
                                                 u16* __restrict__ ctx) {
  __shared__ __align__(16) u16 Ks[2][64 * 64];
  __shared__ __align__(16) unsigned Vt[2][64 * 32];

  const int p = blockIdx.x, bh = blockIdx.y;
  const int bb = bh >> 4, hh = bh & 15;
  const int tid = threadIdx.x;
  const int wave = tid >> 6, lane = tid & 63;
  const int l31 = lane & 31, hi = lane >> 5;

  const u16* Qb = Qg + (size_t)bh * kS * kHD;
  const u16* Kb = Kg + (size_t)bh * kS * kHD;
  const u16* Vb = Vg + (size_t)bh * kS * kHD;

  const float SCL = 0.125f * 1.44269504f;  // 1/sqrt(64) * log2(e)

  const int kp = tid >> 3, do8 = tid & 7;      // V staging map
  const int kkey = lane >> 3, ksl = lane & 7;  // K staging lane map
  const int swzA = (((l31 & 7) ^ (l31 >> 3)) << 2);

  union U4 { unsigned u[4]; bf16x8 v; };

  for (int phase = 0; phase < 2; ++phase) {
    const int qsup = phase ? (15 - p) : p;
    const int s0 = qsup * 128;
    const int qstart = s0 + wave * 32;
    const int ntiles = 2 * qsup + 2;

    // Q B-frags: row q = qstart + l31, k = ds*16 + hi*8 + i
    bf16x8 bq[4];
#pragma unroll
    for (int ds = 0; ds < 4; ++ds)
      bq[ds] = *(const bf16x8*)(Qb + (size_t)(qstart + l31) * 64 + ds * 16 + hi * 8);

    f32x16 acco[2];
    acco[0] = zero16(); acco[1] = zero16();
    float mrow = -3e38f, lrow = 0.f;

    // ---- prologue: V(0)->LDS buf0, V(1)->regs, K(0) gloads ----
    u16x8 va, vb2;
    {
      const u16* vs = Vb + (size_t)(2 * kp) * 64 + do8 * 8;
      va = *(const u16x8*)vs; vb2 = *(const u16x8*)(vs + 64);
    }
#pragma unroll
    for (int i = 0; i < 8; ++i) {
      const int d = do8 * 8 + i;
      Vt[0][d * 32 + (kp ^ ((((d & 7) ^ (d >> 3))) << 2))] =
          (unsigned)va[i] | ((unsigned)vb2[i] << 16);
    }
    {
      const u16* vs = Vb + (size_t)(64 + 2 * kp) * 64 + do8 * 8;
      va = *(const u16x8*)vs; vb2 = *(const u16x8*)(vs + 64);
    }
#pragma unroll
    for (int rep = 0; rep < 2; ++rep) {
      const int key = (wave * 2 + rep) * 8 + kkey;
      gload_lds16(Kb + (size_t)key * 64 + (ksl ^ (key & 7)) * 8,
                  &Ks[0][(wave * 2 + rep) * 512]);
    }

    for (int t = 0; t < ntiles; ++t) {
      const int kv0 = t * 64;
      __syncthreads();  // drains K(t) gloads; syncs V(t) stores; prev compute done

      if (t + 1 < ntiles) {
        const int nb = (t + 1) & 1;
#pragma unroll
        for (int i = 0; i < 8; ++i) {
          const int d = do8 * 8 + i;
          Vt[nb][d * 32 + (kp ^ ((((d & 7) ^ (d >> 3))) << 2))] =
              (unsigned)va[i] | ((unsigned)vb2[i] << 16);
        }
        const int nkv = kv0 + 64;
#pragma unroll
        for (int rep = 0; rep < 2; ++rep) {
          const int key = (wave * 2 + rep) * 8 + kkey;
          gload_lds16(Kb + (size_t)(nkv + key) * 64 + (ksl ^ (key & 7)) * 8,
                      &Ks[nb][(wave * 2 + rep) * 512]);
        }
        if (t + 2 < ntiles) {
          const u16* vs = Vb + (size_t)(kv0 + 128 + 2 * kp) * 64 + do8 * 8;
          va = *(const u16x8*)vs; vb2 = *(const u16x8*)(vs + 64);
        }
      }

      if (kv0 > qstart + 31) continue;  // fully masked for this wave

      const u16* Ksb = &Ks[t & 1][0];
      const unsigned* Vtb = &Vt[t & 1][0];
      const bool pres1 = (kv0 + 32 <= qstart + 31);

      // ---- S^T = K . Q^T  (D[key][q], col=q=l31, row=key reg-mapped) ----
      f32x16 st0 = zero16(), st1 = zero16();
#pragma unroll
      for (int ds = 0; ds < 4; ++ds) {
        const int sl = (((ds << 1) | hi) ^ (l31 & 7)) * 8;
        bf16x8 ak0 = *(const bf16x8*)&Ksb[l31 * 64 + sl];
        st0 = __builtin_amdgcn_mfma_f32_32x32x16_bf16(ak0, bq[ds], st0, 0, 0, 0);
        if (pres1) {
          bf16x8 ak1 = *(const bf16x8*)&Ksb[(32 + l31) * 64 + sl];
          st1 = __builtin_amdgcn_mfma_f32_32x32x16_bf16(ak1, bq[ds], st1, 0, 0, 0);
        }
      }

      // ---- online softmax (per-lane row q = qstart + l31) ----
      const int qv = qstart + l31;
      const int kb0 = kv0 + 4 * hi;
      float sv0[16], sv1[16];
      float ma = -3e38f, mb = -3e38f, mc = -3e38f, md = -3e38f;
      if (kv0 + 31 > qstart) {  // s2=0 may need mask
#pragma unroll
        for (int r = 0; r < 16; ++r) {
          const int key = kb0 + (r & 3) + 8 * (r >> 2);
          float v = st0[r] * SCL;
          v = (key <= qv) ? v : -3e38f;
          sv0[r] = v;
          if ((r & 3) == 0) ma = fmaxf(ma, v);
          else if ((r & 3) == 1) mb = fmaxf(mb, v);
          else if ((r & 3) == 2) mc = fmaxf(mc, v);
          else md = fmaxf(md, v);
        }
      } else {
#pragma unroll
        for (int r = 0; r < 16; ++r) {
          const float v = st0[r] * SCL;
          sv0[r] = v;
          if ((r & 3) == 0) ma = fmaxf(ma, v);
          else if ((r & 3) == 1) mb = fmaxf(mb, v);
          else if ((r & 3) == 2) mc = fmaxf(mc, v);
          else md = fmaxf(md, v);
        }
      }
      if (pres1) {
        const int kb1 = kb0 + 32;
        if (kv0 + 63 > qstart) {
#pragma unroll
          for (int r = 0; r < 16; ++r) {
            const int key = kb1 + (r & 3) + 8 * (r >> 2);
            float v = st1[r] * SCL;
            v = (key <= qv) ? v : -3e38f;
            sv1[r] = v;
            if ((r & 3) == 0) ma = fmaxf(ma, v);
            else if ((r & 3) == 1) mb = fmaxf(mb, v);
            else if ((r & 3) == 2) mc = fmaxf(mc, v);
            else md = fmaxf(md, v);
          }
        } else {
#pragma unroll
          for (int r = 0; r < 16; ++r) {
            const float v = st1[r] * SCL;
            sv1[r] = v;
            if ((r & 3) == 0) ma = fmaxf(ma, v);
            else if ((r & 3) == 1) mb = fmaxf(mb, v);
            else if ((r & 3) == 2) mc = fmaxf(mc, v);
            else md = fmaxf(md, v);
          }
        }
      }
      float tmax = fmaxf(fmaxf(ma, mb), fmaxf(mc, md));
      tmax = fmaxf(tmax, __shfl_xor(tmax, 32, 64));
      const float mn = fmaxf(mrow, tmax);
      const float al = exp2f(mrow - mn);
      mrow = mn;
#pragma unroll
      for (int dg = 0; dg < 2; ++dg)
#pragma unroll
        for (int r = 0; r < 16; ++r) acco[dg][r] *= al;

      float sa = 0.f, sb = 0.f, sc = 0.f, sd = 0.f;

      // ---- s2=0: P, redistribute, PV (kt 0,1) ----
      {
        float pp[16];
#pragma unroll
        for (int r = 0; r < 16; ++r) {
          const float pv = exp2f(sv0[r] - mn);
          pp[r] = pv;
          if ((r & 3) == 0) sa += pv;
          else if ((r & 3) == 1) sb += pv;
          else if ((r & 3) == 2) sc += pv;
          else sd += pv;
        }
        const unsigned qa0 = pkbf(pp[0], pp[1]),  qa1 = pkbf(pp[2], pp[3]);
        const unsigned qb0 = pkbf(pp[4], pp[5]),  qb1 = pkbf(pp[6], pp[7]);
        const unsigned qc0 = pkbf(pp[8], pp[9]),  qc1 = pkbf(pp[10], pp[11]);
        const unsigned qd0 = pkbf(pp[12], pp[13]), qd1 = pkbf(pp[14], pp[15]);
        const unsigned xa0 = __shfl_xor(qa0, 32, 64), xa1 = __shfl_xor(qa1, 32, 64);
        const unsigned xb0 = __shfl_xor(qb0, 32, 64), xb1 = __shfl_xor(qb1, 32, 64);
        const unsigned xc0 = __shfl_xor(qc0, 32, 64), xc1 = __shfl_xor(qc1, 32, 64);
        const unsigned xd0 = __shfl_xor(qd0, 32, 64), xd1 = __shfl_xor(qd1, 32, 64);
        U4 f0, f1;
        f0.u[0] = hi ? xb0 : qa0; f0.u[1] = hi ? xb1 : qa1;
        f0.u[2] = hi ? qb0 : xa0; f0.u[3] = hi ? qb1 : xa1;
        f1.u[0] = hi ? xd0 : qc0; f1.u[1] = hi ? xd1 : qc1;
        f1.u[2] = hi ? qd0 : xc0; f1.u[3] = hi ? qd1 : xc1;
#pragma unroll
        for (int dg = 0; dg < 2; ++dg) {
          const int dbase = (dg * 32 + l31) * 32;
          const int swz = dg ? (swzA ^ 16) : swzA;
          const bf16x8 vf0 = *(const bf16x8*)&Vtb[dbase + ((hi * 4) ^ swz)];
          acco[dg] = __builtin_amdgcn_mfma_f32_32x32x16_bf16(vf0, f0.v, acco[dg], 0, 0, 0);
          const bf16x8 vf1 = *(const bf16x8*)&Vtb[dbase + ((8 + hi * 4) ^ swz)];
          acco[dg] = __builtin_amdgcn_mfma_f32_32x32x16_bf16(vf1, f1.v, acco[dg], 0, 0, 0);
        }
      }
      // ---- s2=1: P, redistribute, PV (kt 2,3) ----
      if (pres1) {
        float pp[16];
#pragma unroll
        for (int r = 0; r < 16; ++r) {
          const float pv = exp2f(sv1[r] - mn);
          pp[r] = pv;
          if ((r & 3) == 0) sa += pv;
          else if ((r & 3) == 1) sb += pv;
          else if ((r & 3) == 2) sc += pv;
          else sd += pv;
        }
        const unsigned qa0 = pkbf(pp[0], pp[1]),  qa1 = pkbf(pp[2], pp[3]);
        const unsigned qb0 = pkbf(pp[4], pp[5]),  qb1 = pkbf(pp[6], pp[7]);
        const unsigned qc0 = pkbf(pp[8], pp[9]),  qc1 = pkbf(pp[10], pp[11]);
        const unsigned qd0 = pkbf(pp[12], pp[13]), qd1 = pkbf(pp[14], pp[15]);
        const unsigned xa0 = __shfl_xor(qa0, 32, 64), xa1 = __shfl_xor(qa1, 32, 64);
        const unsigned xb0 = __shfl_xor(qb0, 32, 64), xb1 = __shfl_xor(qb1, 32, 64);
        const unsigned xc0 = __shfl_xor(qc0, 32, 64), xc1 = __shfl_xor(qc1, 32, 64);
        const unsigned xd0 = __shfl_xor(qd0, 32, 64), xd1 = __shfl_xor(qd1, 32, 64);
        U4 f2, f3;
        f2.u[0] = hi ? xb0 : qa0; f2.u[1] = hi ? xb1 : qa1;
        f2.u[2] = hi ? qb0 : xa0; f2.u[3] = hi ? qb1 : xa1;
        f3.u[0] = hi ? xd0 : qc0; f3.u[1] = hi ? xd1 : qc1;
        f3.u[2] = hi ? qd0 : xc0; f3.u[3] = hi ? qd1 : xc1;
#pragma unroll
        for (int dg = 0; dg < 2; ++dg) {
          const int dbase = (dg * 32 + l31) * 32;
          const int swz = dg ? (swzA ^ 16) : swzA;
          const bf16x8 vf2 = *(const bf16x8*)&Vtb[dbase + ((16 + hi * 4) ^ swz)];
          acco[dg] = __builtin_amdgcn_mfma_f32_32x32x16_bf16(vf2, f2.v, acco[dg], 0, 0, 0);
          const bf16x8 vf3 = *(const bf16x8*)&Vtb[dbase + ((24 + hi * 4) ^ swz)];
          acco[dg] = __builtin_amdgcn_mfma_f32_32x32x16_bf16(vf3, f3.v, acco[dg], 0, 0, 0);
        }
      }

      float ps = (sa + sb) + (sc + sd);
      ps += __shfl_xor(ps, 32, 64);
      lrow = lrow * al + ps;
    }

    // ---- epilogue: O^T -> ctx ; lane writes row q = qstart + l31 ----
    const float rl = 1.0f / lrow;
    u16* orow = ctx + ((size_t)bb * kS + (qstart + l31)) * kD + hh * 64;
#pragma unroll
    for (int dg = 0; dg < 2; ++dg)
#pragma unroll
      for (int rq = 0; rq < 4; ++rq) {
        u16x4 pk;
#pragma unroll
        for (int c = 0; c < 4; ++c) pk[c] = f2bf(acco[dg][rq * 4 + c] * rl);
        *(u16x4*)&orow[dg * 32 + rq * 8 + hi * 4] = pk;
      }
  }
}

// ---------------- launcher ----------------
extern "C" void kernel_launch(void* const* d_in, const int* in_sizes, int n_in,
                              void* d_out, int out_size, void* d_ws, size_t ws_size,
                              hipStream_t stream) {
  const float* x     = (const float*)d_in[0];
  const float* w_qkv = (const float*)d_in[1];
  const float* w_out = (const float*)d_in[2];
  float* out = (float*)d_out;

  u16* ws    = (u16*)d_ws;
  u16* x_bf  = ws;                                  // 8192*1024
  u16* wqkvT = x_bf + (size_t)M1 * K1;              // 3072*1024
  u16* woutT = wqkvT + (size_t)N1 * K1;             // 1024*1024
  u16* qkv   = woutT + (size_t)kD * kD;             // 3 * 64*2048*64
  u16* ctx   = qkv + (size_t)3 * kB * kH * kS * kHD;  // 8192*1024

  k_cast_x<<<M1 * K1 / 1024, 256, 0, stream>>>(x, x_bf);
  k_transpose_cast<<<dim3(N1 / 32, K1 / 32), 256, 0, stream>>>(w_qkv, wqkvT, K1, N1);
  k_transpose_cast<<<dim3(kD / 32, kD / 32), 256, 0, stream>>>(w_out, woutT, kD, kD);

  k_gemm_bt<0><<<dim3(N1 / 128, M1 / 128), 256, 0, stream>>>(x_bf, wqkvT, qkv, nullptr,
                                                             M1, N1, K1);

  const u16* Qg = qkv;
  const u16* Kg = qkv + (size_t)kB * kH * kS * kHD;
  const u16* Vg = qkv + (size_t)2 * kB * kH * kS * kHD;
  k_attn<<<dim3(8, kB * kH), 256, 0, stream>>>(Qg, Kg, Vg, ctx);

  k_gemm_bt<1><<<dim3(kD / 128, M1 / 128), 256, 0, stream>>>(ctx, woutT, nullptr, out,
                                                             M1, kD, K1);
}

// Round 5
// 212.007 us; speedup vs baseline: 2.1619x; 1.0483x over previous
//
#include <hip/hip_runtime.h>
#include <stdint.h>

typedef unsigned short u16;
typedef __attribute__((ext_vector_type(4))) float f32x4;
typedef __attribute__((ext_vector_type(16))) float f32x16;
typedef __attribute__((ext_vector_type(8))) __bf16 bf16x8;
typedef __attribute__((ext_vector_type(8))) u16 u16x8;
typedef __attribute__((ext_vector_type(4))) u16 u16x4;

static constexpr int kB = 4, kS = 2048, kD = 1024, kH = 16, kHD = 64;
static constexpr int M1 = kB * kS;   // 8192
static constexpr int N1 = 3 * kD;    // 3072
static constexpr int K1 = kD;        // 1024

// 1/sqrt(64) * log2(e), folded into Q at GEMM1 epilogue
#define SCLF 0.18033688011112042f
#define MFMA32(a, b, c) __builtin_amdgcn_mfma_f32_32x32x16_bf16((a), (b), (c), 0, 0, 0)

union U4 { unsigned u[4]; bf16x8 v; };

__device__ __forceinline__ u16 f2bf(float f) {
  union { float f; uint32_t u; } c; c.f = f;
  uint32_t u = c.u + 0x7FFFu + ((c.u >> 16) & 1u);   // RNE
  return (u16)(u >> 16);
}

__device__ __forceinline__ unsigned pkbf(float a, float b) {
  union { __bf16 h[2]; unsigned u; } c;
  c.h[0] = (__bf16)a; c.h[1] = (__bf16)b;
  return c.u;
}

__device__ __forceinline__ f32x16 zero16() {
  f32x16 v;
#pragma unroll
  for (int i = 0; i < 16; ++i) v[i] = 0.f;
  return v;
}

__device__ __forceinline__ void gload_lds16(const u16* g, u16* l) {
  __builtin_amdgcn_global_load_lds(
      (const __attribute__((address_space(1))) unsigned int*)g,
      (__attribute__((address_space(3))) unsigned int*)l, 16, 0, 0);
}

// P redistribution: pp[16] (C-layout rows) -> two B-frags (keys base+0..15, +16..31)
__device__ __forceinline__ void packP(const float* pp, int hi, U4& f0, U4& f1) {
  const unsigned qa0 = pkbf(pp[0], pp[1]),   qa1 = pkbf(pp[2], pp[3]);
  const unsigned qb0 = pkbf(pp[4], pp[5]),   qb1 = pkbf(pp[6], pp[7]);
  const unsigned qc0 = pkbf(pp[8], pp[9]),   qc1 = pkbf(pp[10], pp[11]);
  const unsigned qd0 = pkbf(pp[12], pp[13]), qd1 = pkbf(pp[14], pp[15]);
  const unsigned xa0 = __shfl_xor(qa0, 32, 64), xa1 = __shfl_xor(qa1, 32, 64);
  const unsigned xb0 = __shfl_xor(qb0, 32, 64), xb1 = __shfl_xor(qb1, 32, 64);
  const unsigned xc0 = __shfl_xor(qc0, 32, 64), xc1 = __shfl_xor(qc1, 32, 64);
  const unsigned xd0 = __shfl_xor(qd0, 32, 64), xd1 = __shfl_xor(qd1, 32, 64);
  f0.u[0] = hi ? xb0 : qa0; f0.u[1] = hi ? xb1 : qa1;
  f0.u[2] = hi ? qb0 : xa0; f0.u[3] = hi ? qb1 : xa1;
  f1.u[0] = hi ? xd0 : qc0; f1.u[1] = hi ? xd1 : qc1;
  f1.u[2] = hi ? qd0 : xc0; f1.u[3] = hi ? qd1 : xc1;
}

// ---------------- cast kernels ----------------
__global__ __launch_bounds__(256) void k_cast_x(const float* __restrict__ x,
                                                u16* __restrict__ o) {
  int i = (blockIdx.x * 256 + threadIdx.x) * 4;
  f32x4 v = *(const f32x4*)(x + i);
  u16x4 r;
  r[0] = f2bf(v[0]); r[1] = f2bf(v[1]); r[2] = f2bf(v[2]); r[3] = f2bf(v[3]);
  *(u16x4*)(o + i) = r;
}

// w: [K][N] f32  ->  wt: [N][K] bf16   (B^T layout for GEMM)
__global__ __launch_bounds__(256) void k_transpose_cast(const float* __restrict__ w,
                                                        u16* __restrict__ wt,
                                                        int K, int N) {
  __shared__ float t[32][33];
  const int n0 = blockIdx.x * 32, k0 = blockIdx.y * 32;
  const int tx = threadIdx.x & 31, ty = threadIdx.x >> 5;
  for (int r = ty; r < 32; r += 8)
    t[r][tx] = w[(size_t)(k0 + r) * N + n0 + tx];
  __syncthreads();
  for (int r = ty; r < 32; r += 8)
    wt[(size_t)(n0 + r) * K + k0 + tx] = f2bf(t[tx][r]);
}

// ---------------- GEMM (A row-major MxK, BT row-major NxK) ----------------
template <int MODE>
__global__ __launch_bounds__(256) void k_gemm_bt(const u16* __restrict__ A,
                                                 const u16* __restrict__ BT,
                                                 u16* __restrict__ obf,
                                                 float* __restrict__ of,
                                                 int M, int N, int K) {
  typedef __attribute__((ext_vector_type(4))) float f4;
  __shared__ __align__(16) u16 As[128 * 32];
  __shared__ __align__(16) u16 Bs[128 * 32];
  const int tid = threadIdx.x;
  const int wave = tid >> 6, lane = tid & 63;
  const int l15 = lane & 15, l16 = lane >> 4;
  const int row0 = blockIdx.y * 128, col0 = blockIdx.x * 128;
  const int wm = (wave >> 1) * 64, wn = (wave & 1) * 64;

  f4 acc[4][4];
#pragma unroll
  for (int i = 0; i < 4; ++i)
#pragma unroll
    for (int j = 0; j < 4; ++j) acc[i][j] = f4{0.f, 0.f, 0.f, 0.f};

  const int e0 = wave * 512 + lane * 8;
  const int r0 = e0 >> 5, c0 = e0 & 31;
  const int e1 = e0 + 2048;
  const int r1 = e1 >> 5, c1 = e1 & 31;
  const u16* Ab = A + (size_t)row0 * K;
  const u16* Bb = BT + (size_t)col0 * K;

  for (int kt = 0; kt < K; kt += 32) {
    gload_lds16(Ab + (size_t)r0 * K + kt + c0, &As[wave * 512]);
    gload_lds16(Ab + (size_t)r1 * K + kt + c1, &As[2048 + wave * 512]);
    gload_lds16(Bb + (size_t)r0 * K + kt + c0, &Bs[wave * 512]);
    gload_lds16(Bb + (size_t)r1 * K + kt + c1, &Bs[2048 + wave * 512]);
    __syncthreads();
    bf16x8 af[4], bfv[4];
#pragma unroll
    for (int f = 0; f < 4; ++f) {
      af[f]  = *(const bf16x8*)&As[(wm + f * 16 + l15) * 32 + l16 * 8];
      bfv[f] = *(const bf16x8*)&Bs[(wn + f * 16 + l15) * 32 + l16 * 8];
    }
#pragma unroll
    for (int fm = 0; fm < 4; ++fm)
#pragma unroll
      for (int fn = 0; fn < 4; ++fn)
        acc[fm][fn] = __builtin_amdgcn_mfma_f32_16x16x32_bf16(af[fm], bfv[fn],
                                                              acc[fm][fn], 0, 0, 0);
    __syncthreads();
  }

#pragma unroll
  for (int fm = 0; fm < 4; ++fm)
#pragma unroll
    for (int fn = 0; fn < 4; ++fn) {
      const int n = col0 + wn + fn * 16 + l15;
#pragma unroll
      for (int j = 0; j < 4; ++j) {
        const int m = row0 + wm + fm * 16 + l16 * 4 + j;
        float v = acc[fm][fn][j];
        if constexpr (MODE == 0) {
          const int which = n >> 10, d = n & 1023;
          const int h = d >> 6, hd = d & 63;
          const int b = m >> 11, s = m & 2047;
          if (which == 0) v *= SCLF;   // fold softmax scale (log2 dom) into Q
          obf[((((size_t)which * 4 + b) * 16 + h) * 2048 + s) * 64 + hd] = f2bf(v);
        } else {
          of[(size_t)m * N + n] = v;
        }
      }
    }
}

// ---------------- flash attention v4 (swapped 32x32, KVBLK=128, defer-max) ----
// grid: x = 8 (pair index), y = B*H.  Block does q-superblocks {p, 15-p}
// (128 rows each, 4 waves x 32 rows) -> uniform 17 tile-iterations/block.
// S^T = mfma(K, Q): lane owns q = qstart + (lane&31).
// O^T = mfma(Vt_frag, P_frag): m/l/rescale lane-local; l cross-half merged once
// in epilogue. Defer-max: skip rescale+tmax-shfl when max doesn't grow by >8.
// NOTE: a __syncthreads() at the top of each phase prologue is REQUIRED:
// ntiles parity varies, so phase-0's last tile may read Vt[0]/Ks[0] while
// phase-1's prologue overwrites them (round-4 bug).
__global__ __launch_bounds__(256, 2) void k_attn(const u16* __restrict__ Qg,
                                                 const u16* __restrict__ Kg,
                                                 const u16* __restrict__ Vg,
                                                 u16* __restrict__ ctx) {
  __shared__ __align__(16) u16 Ks[2][128 * 64];       // 32 KB
  __shared__ __align__(16) unsigned Vt[2][64 * 64];   // 32 KB  [d][kp]

  const int p = blockIdx.x, bh = blockIdx.y;
  const int bb = bh >> 4, hh = bh & 15;
  const int tid = threadIdx.x;
  const int wave = tid >> 6, lane = tid & 63;
  const int l31 = lane & 31, hi = lane >> 5;

  const u16* Qb = Qg + (size_t)bh * kS * kHD;
  const u16* Kb = Kg + (size_t)bh * kS * kHD;
  const u16* Vb = Vg + (size_t)bh * kS * kHD;

  const int do8 = tid & 7, kpw = tid >> 3;       // V staging: d-slice, kp base
  const int kkey8 = lane >> 3, ksl = lane & 7;   // K staging lane map
  const int swzA = (((l31 & 7) ^ (l31 >> 3)) << 2);

  for (int phase = 0; phase < 2; ++phase) {
    const int qsup = phase ? (15 - p) : p;
    const int s0 = qsup * 128;
    const int qstart = s0 + wave * 32;
    const int ntiles = qsup + 1;   // 128-key tiles

    // Q B-frags: row q = qstart + l31, k = ds*16 + hi*8 + i
    bf16x8 bq[4];
#pragma unroll
    for (int ds = 0; ds < 4; ++ds)
      bq[ds] = *(const bf16x8*)(Qb + (size_t)(qstart + l31) * 64 + ds * 16 + hi * 8);

    f32x16 acco0 = zero16(), acco1 = zero16();
    float mrow = -3e38f, lrowh = 0.f;

    // all waves must be done reading Vt/Ks from the previous phase before the
    // prologue overwrites buffer 0 (race fix; see kernel comment)
    __syncthreads();

    // ---- prologue: V(0)->regs->Vt[0]; V(1)->regs; K(0) gloads ----
    u16x8 va[2], vb[2];
#pragma unroll
    for (int r = 0; r < 2; ++r) {
      const u16* vs = Vb + (size_t)(2 * (kpw + 32 * r)) * 64 + do8 * 8;
      va[r] = *(const u16x8*)vs; vb[r] = *(const u16x8*)(vs + 64);
    }
#pragma unroll
    for (int r = 0; r < 2; ++r)
#pragma unroll
      for (int i = 0; i < 8; ++i) {
        const int d = do8 * 8 + i;
        Vt[0][d * 64 + ((kpw + 32 * r) ^ ((((d & 7) ^ (d >> 3))) << 2))] =
            (unsigned)va[r][i] | ((unsigned)vb[r][i] << 16);
      }
#pragma unroll
    for (int r = 0; r < 2; ++r) {
      const u16* vs = Vb + (size_t)(128 + 2 * (kpw + 32 * r)) * 64 + do8 * 8;
      va[r] = *(const u16x8*)vs; vb[r] = *(const u16x8*)(vs + 64);
    }
#pragma unroll
    for (int r = 0; r < 4; ++r) {
      const int key = wave * 32 + r * 8 + kkey8;
      gload_lds16(Kb + (size_t)key * 64 + (ksl ^ (key & 7)) * 8,
                  &Ks[0][(wave * 4 + r) * 512]);
    }

    for (int t = 0; t < ntiles; ++t) {
      const int kv0 = t * 128;
      __syncthreads();  // drains K(t) gloads; syncs V(t) stores; prev reads done

      if (t + 1 < ntiles) {
        const int nb = (t + 1) & 1;
#pragma unroll
        for (int r = 0; r < 2; ++r)
#pragma unroll
          for (int i = 0; i < 8; ++i) {
            const int d = do8 * 8 + i;
            Vt[nb][d * 64 + ((kpw + 32 * r) ^ ((((d & 7) ^ (d >> 3))) << 2))] =
                (unsigned)va[r][i] | ((unsigned)vb[r][i] << 16);
          }
#pragma unroll
        for (int r = 0; r < 4; ++r) {
          const int key = wave * 32 + r * 8 + kkey8;
          gload_lds16(Kb + (size_t)(kv0 + 128 + key) * 64 + (ksl ^ (key & 7)) * 8,
                      &Ks[nb][(wave * 4 + r) * 512]);
        }
        if (t + 2 < ntiles) {
#pragma unroll
          for (int r = 0; r < 2; ++r) {
            const u16* vs = Vb + (size_t)(kv0 + 256 + 2 * (kpw + 32 * r)) * 64 + do8 * 8;
            va[r] = *(const u16x8*)vs; vb[r] = *(const u16x8*)(vs + 64);
          }
        }
      }

      const u16* Ksb = &Ks[t & 1][0];
      const unsigned* Vtb = &Vt[t & 1][0];
      const int qv = qstart + l31;

#pragma unroll
      for (int h = 0; h < 2; ++h) {
        const int kb = kv0 + 64 * h;
        if (kb > qstart + 31) continue;   // wave-uniform skip
        const int krow = 64 * h;
        const bool pres1 = (kb + 32 <= qstart + 31);

        // ---- QK^T ----
        f32x16 st0 = zero16(), st1 = zero16();
        __builtin_amdgcn_s_setprio(1);
#pragma unroll
        for (int ds = 0; ds < 4; ++ds) {
          const int sl = (((ds << 1) | hi) ^ (l31 & 7)) * 8;
          bf16x8 ak0 = *(const bf16x8*)&Ksb[(krow + l31) * 64 + sl];
          st0 = MFMA32(ak0, bq[ds], st0);
          if (pres1) {
            bf16x8 ak1 = *(const bf16x8*)&Ksb[(krow + 32 + l31) * 64 + sl];
            st1 = MFMA32(ak1, bq[ds], st1);
          }
        }
        __builtin_amdgcn_s_setprio(0);

        // ---- mask into st, local max ----
        float tl = -3e38f;
        if (kb + 31 > qstart) {
          const int kb0 = kb + 4 * hi;
#pragma unroll
          for (int r = 0; r < 16; ++r) {
            const int key = kb0 + (r & 3) + 8 * (r >> 2);
            float v = st0[r];
            v = (key <= qv) ? v : -3e38f;
            st0[r] = v;
            tl = fmaxf(tl, v);
          }
        } else {
#pragma unroll
          for (int r = 0; r < 16; ++r) tl = fmaxf(tl, st0[r]);
        }
        if (pres1) {
          if (kb + 63 > qstart) {
            const int kb1 = kb + 32 + 4 * hi;
#pragma unroll
            for (int r = 0; r < 16; ++r) {
              const int key = kb1 + (r & 3) + 8 * (r >> 2);
              float v = st1[r];
              v = (key <= qv) ? v : -3e38f;
              st1[r] = v;
              tl = fmaxf(tl, v);
            }
          } else {
#pragma unroll
            for (int r = 0; r < 16; ++r) tl = fmaxf(tl, st1[r]);
          }
        }

        // ---- defer-max decision ----
        float mn;
        if (__all(tl <= mrow + 8.0f)) {
          mn = mrow;                      // deferred: no shfl, no rescale
        } else {
          const float tj = fmaxf(tl, __shfl_xor(tl, 32, 64));
          mn = fmaxf(mrow, tj);
          const float al = exp2f(mrow - mn);
          mrow = mn;
          lrowh *= al;
#pragma unroll
          for (int r = 0; r < 16; ++r) { acco0[r] *= al; acco1[r] *= al; }
        }

        // ---- chunk 0 (keys kb .. kb+31) ----
        {
          float pp[16];
#pragma unroll
          for (int r = 0; r < 16; ++r) pp[r] = exp2f(st0[r] - mn);
          const float t0 = (pp[0] + pp[1]) + (pp[2] + pp[3]);
          const float t1 = (pp[4] + pp[5]) + (pp[6] + pp[7]);
          const float t2 = (pp[8] + pp[9]) + (pp[10] + pp[11]);
          const float t3 = (pp[12] + pp[13]) + (pp[14] + pp[15]);
          lrowh += (t0 + t1) + (t2 + t3);
          U4 f0, f1;
          packP(pp, hi, f0, f1);
          const int c0 = 32 * h;
          __builtin_amdgcn_s_setprio(1);
          {
            const int dbase = l31 * 64, sz = swzA;
            const bf16x8 vfa = *(const bf16x8*)&Vtb[dbase + ((c0 + hi * 4) ^ sz)];
            acco0 = MFMA32(vfa, f0.v, acco0);
            const bf16x8 vfb = *(const bf16x8*)&Vtb[dbase + ((c0 + 8 + hi * 4) ^ sz)];
            acco0 = MFMA32(vfb, f1.v, acco0);
          }
          {
            const int dbase = (32 + l31) * 64, sz = swzA ^ 16;
            const bf16x8 vfa = *(const bf16x8*)&Vtb[dbase + ((c0 + hi * 4) ^ sz)];
            acco1 = MFMA32(vfa, f0.v, acco1);
            const bf16x8 vfb = *(const bf16x8*)&Vtb[dbase + ((c0 + 8 + hi * 4) ^ sz)];
            acco1 = MFMA32(vfb, f1.v, acco1);
          }
          __builtin_amdgcn_s_setprio(0);
        }
        // ---- chunk 1 (keys kb+32 .. kb+63) ----
        if (pres1) {
          float pp[16];
#pragma unroll
          for (int r = 0; r < 16; ++r) pp[r] = exp2f(st1[r] - mn);
          const float t0 = (pp[0] + pp[1]) + (pp[2] + pp[3]);
          const float t1 = (pp[4] + pp[5]) + (pp[6] + pp[7]);
          const float t2 = (pp[8] + pp[9]) + (pp[10] + pp[11]);
          const float t3 = (pp[12] + pp[13]) + (pp[14] + pp[15]);
          lrowh += (t0 + t1) + (t2 + t3);
          U4 f0, f1;
          packP(pp, hi, f0, f1);
          const int c1 = 32 * h + 16;
          __builtin_amdgcn_s_setprio(1);
          {
            const int dbase = l31 * 64, sz = swzA;
            const bf16x8 vfa = *(const bf16x8*)&Vtb[dbase + ((c1 + hi * 4) ^ sz)];
            acco0 = MFMA32(vfa, f0.v, acco0);
            const bf16x8 vfb = *(const bf16x8*)&Vtb[dbase + ((c1 + 8 + hi * 4) ^ sz)];
            acco0 = MFMA32(vfb, f1.v, acco0);
          }
          {
            const int dbase = (32 + l31) * 64, sz = swzA ^ 16;
            const bf16x8 vfa = *(const bf16x8*)&Vtb[dbase + ((c1 + hi * 4) ^ sz)];
            acco1 = MFMA32(vfa, f0.v, acco1);
            const bf16x8 vfb = *(const bf16x8*)&Vtb[dbase + ((c1 + 8 + hi * 4) ^ sz)];
            acco1 = MFMA32(vfb, f1.v, acco1);
          }
          __builtin_amdgcn_s_setprio(0);
        }
      }
    }

    // ---- epilogue: merge l across halves once; write O^T rows ----
    const float lrow = lrowh + __shfl_xor(lrowh, 32, 64);
    const float rl = 1.0f / lrow;
    u16* orow = ctx + ((size_t)bb * kS + (qstart + l31)) * kD + hh * 64;
#pragma unroll
    for (int rq = 0; rq < 4; ++rq) {
      u16x4 pk0, pk1;
#pragma unroll
      for (int c = 0; c < 4; ++c) {
        pk0[c] = f2bf(acco0[rq * 4 + c] * rl);
        pk1[c] = f2bf(acco1[rq * 4 + c] * rl);
      }
      *(u16x4*)&orow[rq * 8 + hi * 4] = pk0;
      *(u16x4*)&orow[32 + rq * 8 + hi * 4] = pk1;
    }
  }
}

// ---------------- launcher ----------------
extern "C" void kernel_launch(void* const* d_in, const int* in_sizes, int n_in,
                              void* d_out, int out_size, void* d_ws, size_t ws_size,
                              hipStream_t stream) {
  const float* x     = (const float*)d_in[0];
  const float* w_qkv = (const float*)d_in[1];
  const float* w_out = (const float*)d_in[2];
  float* out = (float*)d_out;

  u16* ws    = (u16*)d_ws;
  u16* x_bf  = ws;                                  // 8192*1024
  u16* wqkvT = x_bf + (size_t)M1 * K1;              // 3072*1024
  u16* woutT = wqkvT + (size_t)N1 * K1;              // 1024*1024
  u16* qkv   = woutT + (size_t)kD * kD;             // 3 * 64*2048*64
  u16* ctx   = qkv + (size_t)3 * kB * kH * kS * kHD;  // 8192*1024

  k_cast_x<<<M1 * K1 / 1024, 256, 0, stream>>>(x, x_bf);
  k_transpose_cast<<<dim3(N1 / 32, K1 / 32), 256, 0, stream>>>(w_qkv, wqkvT, K1, N1);
  k_transpose_cast<<<dim3(kD / 32, kD / 32), 256, 0, stream>>>(w_out, woutT, kD, kD);

  k_gemm_bt<0><<<dim3(N1 / 128, M1 / 128), 256, 0, stream>>>(x_bf, wqkvT, qkv, nullptr,
                                                             M1, N1, K1);

  const u16* Qg = qkv;
  const u16* Kg = qkv + (size_t)kB * kH * kS * kHD;
  const u16* Vg = qkv + (size_t)2 * kB * kH * kS * kHD;
  k_attn<<<dim3(8, kB * kH), 256, 0, stream>>>(Qg, Kg, Vg, ctx);

  k_gemm_bt<1><<<dim3(kD / 128, M1 / 128), 256, 0, stream>>>(ctx, woutT, nullptr, out,
                                                             M1, kD, K1);
}